// Round 15
// baseline (211.567 us; speedup 1.0000x reference)
//
#include <hip/hip_runtime.h>
#include <math.h>

#define LSEQ   2048
#define DMODEL 1024
#define DINNER 2048
#define DSTATE 16
#define DTRANK 64
#define XCOLS  96   // dt_rank + 2*d_state
#define CL     64   // scan chunk length
#define NC     (LSEQ/CL)          // 32 chunks -> one 32-lane scan group
#define SSTATE (DINNER*DSTATE)    // 32768 scalar recurrences

typedef __attribute__((ext_vector_type(8))) short bf16x8;
typedef __attribute__((ext_vector_type(4))) float f32x4;
typedef unsigned short ushort_t;
typedef unsigned int uint_t;

__device__ __forceinline__ float siluf(float v) { return v / (1.f + __expf(-v)); }

// RNE float -> bf16 bits (finite inputs)
__device__ __forceinline__ ushort_t f2bf(float f) {
    uint_t u = __float_as_uint(f);
    u += 0x7FFFu + ((u >> 16) & 1u);
    return (ushort_t)(u >> 16);
}
__device__ __forceinline__ float bf2f(ushort_t u) {
    return __uint_as_float((uint_t)u << 16);
}

__device__ __forceinline__ bf16x8 cvt8(float4 lo, float4 hi) {
    bf16x8 r;
    r[0] = (short)f2bf(lo.x); r[1] = (short)f2bf(lo.y);
    r[2] = (short)f2bf(lo.z); r[3] = (short)f2bf(lo.w);
    r[4] = (short)f2bf(hi.x); r[5] = (short)f2bf(hi.y);
    r[6] = (short)f2bf(hi.z); r[7] = (short)f2bf(hi.w);
    return r;
}

// ---------------------------------------------------------------------------
// fused f32 -> bf16 cast for 5 tensors + zero-fill of xdbl.
// ---------------------------------------------------------------------------
__global__ __launch_bounds__(256)
void cast6_kernel(const float* __restrict__ s0, ushort_t* __restrict__ d0, int c0,
                  const float* __restrict__ s1, ushort_t* __restrict__ d1, int c1,
                  const float* __restrict__ s2, ushort_t* __restrict__ d2, int c2,
                  const float* __restrict__ s3, ushort_t* __restrict__ d3, int c3,
                  const float* __restrict__ s4, ushort_t* __restrict__ d4, int c4,
                  float* __restrict__ z0, int cz)
{
    int i = (blockIdx.x * 256 + threadIdx.x) * 8;
    int tot = c0 + c1 + c2 + c3 + c4;
    if (i < tot) {
        const float* s; ushort_t* d;
        if (i < c0)                { s = s0 + i;                  d = d0 + i; }
        else if (i < c0+c1)        { s = s1 + (i-c0);             d = d1 + (i-c0); }
        else if (i < c0+c1+c2)     { s = s2 + (i-c0-c1);          d = d2 + (i-c0-c1); }
        else if (i < c0+c1+c2+c3)  { s = s3 + (i-c0-c1-c2);       d = d3 + (i-c0-c1-c2); }
        else                       { s = s4 + (i-c0-c1-c2-c3);    d = d4 + (i-c0-c1-c2-c3); }
        *(bf16x8*)d = cvt8(*(const float4*)s, *(const float4*)(s + 4));
    } else if (i < tot + cz) {
        float* z = z0 + (i - tot);
        *(float4*)z       = make_float4(0.f, 0.f, 0.f, 0.f);
        *(float4*)(z + 4) = make_float4(0.f, 0.f, 0.f, 0.f);
    }
}

// ---------------------------------------------------------------------------
// bf16 MFMA GEMM — r5 measured-best structure (2-phase dbuf, BK=32, vmcnt(4),
// no swizzle: default dispatch order gives min FETCH, r13/r14).
// EPI=0: fp32 store to Cp = C + blockIdx.z*partStride (split-K, no atomics).
// EPI=1: in_proj fused epilogue — x-half -> bf16 Xb; z-half -> silu -> Gz.
// LDS per buf: [4 kb][128 row][8 elem] -> SQ_LDS_BANK_CONFLICT == 0.
// ---------------------------------------------------------------------------
__device__ __forceinline__ void stage_tile(const ushort_t* __restrict__ A,
                                           const ushort_t* __restrict__ B,
                                           ushort_t* As, ushort_t* Bs,
                                           int m0, int n0, int K, int k0, int tid)
{
#pragma unroll
    for (int j = 0; j < 2; j++) {
        const int c   = j * 256 + tid;   // 16B chunk index 0..511
        const int row = c & 127;
        const int kbi = c >> 7;          // 0..3
        __builtin_amdgcn_global_load_lds(
            (const __attribute__((address_space(1))) uint_t*)(A + (size_t)(m0 + row) * K + k0 + kbi * 8),
            (__attribute__((address_space(3))) uint_t*)((char*)As + c * 16), 16, 0, 0);
        __builtin_amdgcn_global_load_lds(
            (const __attribute__((address_space(1))) uint_t*)(B + (size_t)(n0 + row) * K + k0 + kbi * 8),
            (__attribute__((address_space(3))) uint_t*)((char*)Bs + c * 16), 16, 0, 0);
    }
}

template<int EPI, int SPLITK>
__global__ __launch_bounds__(256)
void gemm_bf16(const ushort_t* __restrict__ A,
               const ushort_t* __restrict__ B,
               float* __restrict__ C,
               ushort_t* __restrict__ Xb,
               ushort_t* __restrict__ Gz,
               int M, int N, int K, size_t partStride)
{
    __shared__ ushort_t As[2][4096];
    __shared__ ushort_t Bs[2][4096];

    const int tid  = threadIdx.x;
    const int wid  = tid >> 6;
    const int lane = tid & 63;
    const int m0 = blockIdx.x * 128;
    const int n0 = blockIdx.y * 128;
    const int kcnt  = K / SPLITK;
    const int kbase = (SPLITK > 1) ? blockIdx.z * kcnt : 0;
    const int NT = kcnt / 32;
    float* Cp = (EPI == 0) ? C + (size_t)blockIdx.z * partStride : C;
    const int wr = (wid >> 1) * 64;
    const int wc = (wid & 1) * 64;
    const int lr = lane & 15;
    const int kbq = lane >> 4;

    f32x4 acc[4][4];
#pragma unroll
    for (int m = 0; m < 4; m++)
#pragma unroll
        for (int n = 0; n < 4; n++)
            acc[m][n] = (f32x4){0.f, 0.f, 0.f, 0.f};

    stage_tile(A, B, As[0], Bs[0], m0, n0, K, kbase, tid);

    for (int t = 0; t < NT; t++) {
        const int cur = t & 1;
        if (t + 1 < NT) {
            stage_tile(A, B, As[cur ^ 1], Bs[cur ^ 1], m0, n0, K, kbase + (t + 1) * 32, tid);
            asm volatile("s_waitcnt vmcnt(4)" ::: "memory");
        } else {
            asm volatile("s_waitcnt vmcnt(0)" ::: "memory");
        }
        __builtin_amdgcn_s_barrier();
        __builtin_amdgcn_sched_barrier(0);

        bf16x8 af[4], bfr[4];
#pragma unroll
        for (int m = 0; m < 4; m++)
            af[m] = *(const bf16x8*)&As[cur][(kbq * 128 + wr + m * 16 + lr) * 8];
#pragma unroll
        for (int n = 0; n < 4; n++)
            bfr[n] = *(const bf16x8*)&Bs[cur][(kbq * 128 + wc + n * 16 + lr) * 8];
#pragma unroll
        for (int m = 0; m < 4; m++)
#pragma unroll
            for (int n = 0; n < 4; n++)
                acc[m][n] = __builtin_amdgcn_mfma_f32_16x16x32_bf16(af[m], bfr[n], acc[m][n], 0, 0, 0);

        __builtin_amdgcn_sched_barrier(0);
        __builtin_amdgcn_s_barrier();
    }

    const int er = (lane >> 4) * 4;
    const int ec = lane & 15;
    if (EPI == 0) {
#pragma unroll
        for (int m = 0; m < 4; m++) {
            const int grow = m0 + wr + m * 16 + er;
#pragma unroll
            for (int n = 0; n < 4; n++) {
                const int gcol = n0 + wc + n * 16 + ec;
#pragma unroll
                for (int r = 0; r < 4; r++)
                    Cp[(size_t)(grow + r) * N + gcol] = acc[m][n][r];
            }
        }
    } else {
        const bool xside = (n0 < DINNER);   // uniform per block
#pragma unroll
        for (int m = 0; m < 4; m++) {
            const int grow = m0 + wr + m * 16 + er;
#pragma unroll
            for (int n = 0; n < 4; n++) {
                const int gcol = n0 + wc + n * 16 + ec;
#pragma unroll
                for (int r = 0; r < 4; r++) {
                    float v = acc[m][n][r];
                    if (xside)
                        Xb[(size_t)(grow + r) * DINNER + gcol] = f2bf(v);
                    else
                        Gz[(size_t)(grow + r) * DINNER + (gcol - DINNER)] = f2bf(siluf(v));
                }
            }
        }
    }
}

// ---------------------------------------------------------------------------
// Sum NP fp32 partials (each n elems) into out. float4 per thread.
// ---------------------------------------------------------------------------
template<int NP>
__global__ __launch_bounds__(256)
void addp_kernel(const float* __restrict__ parts, float* __restrict__ out, int n)
{
    int i = (blockIdx.x * 256 + threadIdx.x) * 4;
    if (i >= n) return;
    float4 s = *(const float4*)(parts + i);
#pragma unroll
    for (int p = 1; p < NP; p++) {
        float4 v = *(const float4*)(parts + (size_t)p * n + i);
        s.x += v.x; s.y += v.y; s.z += v.z; s.w += v.w;
    }
    *(float4*)(out + i) = s;
}

// ---------------------------------------------------------------------------
// x_dbl GEMM: direct-fragment MFMA, split-K=16, fp32 atomics on 786 KB output.
// ---------------------------------------------------------------------------
__global__ __launch_bounds__(256)
void gemm_xdbl(const ushort_t* __restrict__ A,
               const ushort_t* __restrict__ B,
               float* __restrict__ Cout)
{
    const int tid = threadIdx.x, wid = tid >> 6, lane = tid & 63;
    const int m0 = blockIdx.x * 128;
    const int kbase = blockIdx.z * 128;
    const int wr = (wid >> 1) * 64;
    const int wc = (wid & 1) * 48;
    const int lr = lane & 15;
    const int kq = (lane >> 4) * 8;

    f32x4 acc[4][3];
#pragma unroll
    for (int m = 0; m < 4; m++)
#pragma unroll
        for (int n = 0; n < 3; n++)
            acc[m][n] = (f32x4){0.f, 0.f, 0.f, 0.f};

#pragma unroll
    for (int ks = 0; ks < 4; ks++) {
        const int k0 = kbase + ks * 32;
        bf16x8 af[4], bfr[3];
#pragma unroll
        for (int m = 0; m < 4; m++)
            af[m] = *(const bf16x8*)(A + (size_t)(m0 + wr + m * 16 + lr) * DINNER + k0 + kq);
#pragma unroll
        for (int n = 0; n < 3; n++)
            bfr[n] = *(const bf16x8*)(B + (size_t)(wc + n * 16 + lr) * DINNER + k0 + kq);
#pragma unroll
        for (int m = 0; m < 4; m++)
#pragma unroll
            for (int n = 0; n < 3; n++)
                acc[m][n] = __builtin_amdgcn_mfma_f32_16x16x32_bf16(af[m], bfr[n], acc[m][n], 0, 0, 0);
    }

    const int er = (lane >> 4) * 4;
    const int ec = lane & 15;
#pragma unroll
    for (int m = 0; m < 4; m++)
#pragma unroll
        for (int n = 0; n < 3; n++)
#pragma unroll
            for (int r = 0; r < 4; r++)
                atomicAdd(&Cout[(size_t)(m0 + wr + m * 16 + er + r) * XCOLS + wc + n * 16 + ec],
                          acc[m][n][r]);
}

// ---------------------------------------------------------------------------
// dt GEMM: dtmb = bf16(softplus(xdbl[:, :64] @ Wdtb^T + b_dt)).
// ---------------------------------------------------------------------------
__global__ __launch_bounds__(256)
void gemm_dt(const float* __restrict__ Axd,
             const ushort_t* __restrict__ Bw,
             const float* __restrict__ bias,
             ushort_t* __restrict__ dtmb)
{
    const int tid = threadIdx.x, wid = tid >> 6, lane = tid & 63;
    const int m0 = blockIdx.x * 128;
    const int n0 = blockIdx.y * 128;
    const int wr = (wid >> 1) * 64;
    const int wc = (wid & 1) * 64;
    const int lr = lane & 15;
    const int kq = (lane >> 4) * 8;

    f32x4 acc[4][4];
#pragma unroll
    for (int m = 0; m < 4; m++)
#pragma unroll
        for (int n = 0; n < 4; n++)
            acc[m][n] = (f32x4){0.f, 0.f, 0.f, 0.f};

#pragma unroll
    for (int kk = 0; kk < 2; kk++) {
        bf16x8 af[4], bfr[4];
#pragma unroll
        for (int m = 0; m < 4; m++) {
            const float* p = Axd + (size_t)(m0 + wr + m * 16 + lr) * XCOLS + kk * 32 + kq;
            af[m] = cvt8(*(const float4*)p, *(const float4*)(p + 4));
        }
#pragma unroll
        for (int n = 0; n < 4; n++)
            bfr[n] = *(const bf16x8*)(Bw + (size_t)(n0 + wc + n * 16 + lr) * DTRANK + kk * 32 + kq);
#pragma unroll
        for (int m = 0; m < 4; m++)
#pragma unroll
            for (int n = 0; n < 4; n++)
                acc[m][n] = __builtin_amdgcn_mfma_f32_16x16x32_bf16(af[m], bfr[n], acc[m][n], 0, 0, 0);
    }

    const int er = (lane >> 4) * 4;
    const int ec = lane & 15;
#pragma unroll
    for (int m = 0; m < 4; m++)
#pragma unroll
        for (int n = 0; n < 4; n++) {
            const int gcol = n0 + wc + n * 16 + ec;
            const float bv = bias[gcol];
#pragma unroll
            for (int r = 0; r < 4; r++) {
                float c = acc[m][n][r] + bv;
                c = (c > 20.f) ? c : log1pf(__expf(c));
                dtmb[(size_t)(m0 + wr + m * 16 + er + r) * DINNER + gcol] = f2bf(c);
            }
        }
}

// ---------------------------------------------------------------------------
// Depthwise causal conv (width 4) + bias + SiLU, all-bf16 I/O.
// ---------------------------------------------------------------------------
__global__ __launch_bounds__(256)
void conv_silu_kernel(const ushort_t* __restrict__ xinb,
                      const float* __restrict__ conv_w,
                      const float* __restrict__ conv_b,
                      ushort_t* __restrict__ xcb)
{
    int idx = blockIdx.x * 256 + threadIdx.x;
    if (idx >= LSEQ * DINNER) return;
    int t = idx / DINNER;
    int d = idx - t * DINNER;
    float acc = conv_b[d];
#pragma unroll
    for (int j = 0; j < 4; j++) {
        int tt = t - 3 + j;
        if (tt >= 0)
            acc = fmaf(conv_w[d*4 + j], bf2f(xinb[(size_t)tt * DINNER + d]), acc);
    }
    xcb[idx] = f2bf(siluf(acc));
}

// ---------------------------------------------------------------------------
// Chunked parallel selective scan, CL=64, packed float2 state {Aprod, h}.
// Phase 1: local scan per chunk -> state[c][n][d] = {exp(a*sum_dt), h_end}.
// Phase 2: 32-lane Hillis-Steele scan over the 32 chunks of each (d,n) chain
//          (map-compose (A2,h2)o(A1,h1) = (A1A2, A2h1+h2)); overwrites
//          state.y with the EXCLUSIVE carry-in for that chunk.
// Phase 3: re-scan from carry-in, contract with C, D-skip + gz gate -> bf16 y.
// ---------------------------------------------------------------------------
__global__ __launch_bounds__(256)
void scan_phase1(const ushort_t* __restrict__ dtmb,
                 const float* __restrict__ xdbl,
                 const ushort_t* __restrict__ xcb,
                 const float* __restrict__ A_log,
                 float2* __restrict__ state)
{
    __shared__ float Bs[CL][16];
    const int tid = threadIdx.x;
    const int d = blockIdx.x * 256 + tid;
    const int c = blockIdx.y;
    const int t0 = c * CL;

    {   // stage B chunk tile: CL*16 = 1024 floats, 4/thread
        int t = tid >> 2, n = (tid & 3) * 4;
        float4 v = *(const float4*)&xdbl[(size_t)(t0 + t) * XCOLS + DTRANK + n];
        Bs[t][n] = v.x; Bs[t][n+1] = v.y; Bs[t][n+2] = v.z; Bs[t][n+3] = v.w;
    }

    float a[16];
#pragma unroll
    for (int q = 0; q < 4; q++) {
        f32x4 v = *(const f32x4*)&A_log[(size_t)d * DSTATE + q * 4];
#pragma unroll
        for (int j = 0; j < 4; j++) a[q * 4 + j] = -__expf(v[j]);
    }
    float h[16];
#pragma unroll
    for (int n = 0; n < 16; n++) h[n] = 0.f;
    float sdt = 0.f;

    __syncthreads();

    float dtv = bf2f(dtmb[(size_t)t0 * DINNER + d]);
    float xv  = bf2f(xcb[(size_t)t0 * DINNER + d]);
    for (int tt = 0; tt < CL; tt++) {
        int tn_ = t0 + ((tt + 1 < CL) ? tt + 1 : tt);
        float dtv_n = bf2f(dtmb[(size_t)tn_ * DINNER + d]);
        float xv_n  = bf2f(xcb[(size_t)tn_ * DINNER + d]);

        f32x4 Bq[4];
#pragma unroll
        for (int q = 0; q < 4; q++) Bq[q] = *(const f32x4*)&Bs[tt][q * 4];
        float dtx = dtv * xv;
        sdt += dtv;
#pragma unroll
        for (int n = 0; n < 16; n++) {
            float e = __expf(dtv * a[n]);
            h[n] = fmaf(e, h[n], dtx * Bq[n >> 2][n & 3]);
        }
        dtv = dtv_n; xv = xv_n;
    }

#pragma unroll
    for (int n = 0; n < 16; n++)
        state[(size_t)c * SSTATE + (size_t)n * DINNER + d] =
            make_float2(__expf(a[n] * sdt), h[n]);
}

__global__ __launch_bounds__(256)
void scan_phase2(float2* __restrict__ state)
{
    const int lane32 = threadIdx.x & 31;                    // chunk index
    const int chain  = blockIdx.x * 8 + (threadIdx.x >> 5); // (n,d) chain
    const size_t off = (size_t)lane32 * SSTATE + chain;
    float2 s = state[off];
    float A = s.x, h = s.y;
#pragma unroll
    for (int dlt = 1; dlt < 32; dlt <<= 1) {
        float Ap = __shfl_up(A, dlt, 32);
        float hp = __shfl_up(h, dlt, 32);
        if (lane32 >= dlt) { h = fmaf(A, hp, h); A = A * Ap; }
    }
    // inclusive -> exclusive carry-in for this chunk
    float carry = __shfl_up(h, 1, 32);
    if (lane32 == 0) carry = 0.f;
    ((float*)&state[off])[1] = carry;
}

__global__ __launch_bounds__(256)
void scan_phase3(const ushort_t* __restrict__ dtmb,
                 const float* __restrict__ xdbl,
                 const ushort_t* __restrict__ xcb,
                 const float* __restrict__ A_log,
                 const float* __restrict__ Dp,
                 const ushort_t* __restrict__ gz,
                 const float2* __restrict__ state,
                 ushort_t* __restrict__ yb)
{
    __shared__ float Bs[CL][16];
    __shared__ float Cs[CL][16];
    const int tid = threadIdx.x;
    const int d = blockIdx.x * 256 + tid;
    const int c = blockIdx.y;
    const int t0 = c * CL;

    {   // stage B and C chunk tiles: 2 * CL*16 floats; 8 floats/thread
        int r = tid & 127;
        int t = r >> 1, nb = (r & 1) * 8;
        const float* src = &xdbl[(size_t)(t0 + t) * XCOLS + DTRANK + ((tid < 128) ? 0 : DSTATE) + nb];
        float* dst = (tid < 128) ? &Bs[t][nb] : &Cs[t][nb];
        float4 v0 = *(const float4*)src;
        float4 v1 = *(const float4*)(src + 4);
        dst[0]=v0.x; dst[1]=v0.y; dst[2]=v0.z; dst[3]=v0.w;
        dst[4]=v1.x; dst[5]=v1.y; dst[6]=v1.z; dst[7]=v1.w;
    }

    float a[16];
#pragma unroll
    for (int q = 0; q < 4; q++) {
        f32x4 v = *(const f32x4*)&A_log[(size_t)d * DSTATE + q * 4];
#pragma unroll
        for (int j = 0; j < 4; j++) a[q * 4 + j] = -__expf(v[j]);
    }
    const float Dv = Dp[d];
    float h[16];
#pragma unroll
    for (int n = 0; n < 16; n++)
        h[n] = state[(size_t)c * SSTATE + (size_t)n * DINNER + d].y;

    __syncthreads();

    float dtv = bf2f(dtmb[(size_t)t0 * DINNER + d]);
    float xv  = bf2f(xcb[(size_t)t0 * DINNER + d]);
    for (int tt = 0; tt < CL; tt++) {
        const int t = t0 + tt;
        int tn_ = t0 + ((tt + 1 < CL) ? tt + 1 : tt);
        float dtv_n = bf2f(dtmb[(size_t)tn_ * DINNER + d]);
        float xv_n  = bf2f(xcb[(size_t)tn_ * DINNER + d]);
        float gzv   = bf2f(gz[(size_t)t * DINNER + d]);

        f32x4 Bq[4], Cq[4];
#pragma unroll
        for (int q = 0; q < 4; q++) {
            Bq[q] = *(const f32x4*)&Bs[tt][q * 4];
            Cq[q] = *(const f32x4*)&Cs[tt][q * 4];
        }
        float dtx = dtv * xv;
        float y = 0.f;
#pragma unroll
        for (int n = 0; n < 16; n++) {
            float e = __expf(dtv * a[n]);
            h[n] = fmaf(e, h[n], dtx * Bq[n >> 2][n & 3]);
            y = fmaf(h[n], Cq[n >> 2][n & 3], y);
        }
        yb[(size_t)t * DINNER + d] = f2bf((y + Dv * xv) * gzv);
        dtv = dtv_n; xv = xv_n;
    }
}

// ---------------------------------------------------------------------------
extern "C" void kernel_launch(void* const* d_in, const int* in_sizes, int n_in,
                              void* d_out, int out_size, void* d_ws, size_t ws_size,
                              hipStream_t stream)
{
    const float* x      = (const float*)d_in[0];
    const float* W_in   = (const float*)d_in[1];
    const float* conv_w = (const float*)d_in[2];
    const float* conv_b = (const float*)d_in[3];
    const float* W_x    = (const float*)d_in[4];
    const float* W_dt   = (const float*)d_in[5];
    const float* b_dt   = (const float*)d_in[6];
    const float* A_log  = (const float*)d_in[7];
    const float* D_par  = (const float*)d_in[8];
    const float* W_out  = (const float*)d_in[9];
    float* out = (float*)d_out;
    float* ws  = (float*)d_ws;

    // fp32 region
    float*  xdbl  = ws;                                        // 196608 f32
    float2* state = (float2*)(xdbl + (size_t)LSEQ * XCOLS);    // NC*SSTATE f2 = 8 MB
    // bf16 region
    ushort_t* xb   = (ushort_t*)(state + (size_t)NC * SSTATE); // 2M  (x cast)
    ushort_t* Wib  = xb   + (size_t)LSEQ * DMODEL;             // 4M  (W_in)
    ushort_t* Wob  = Wib  + (size_t)(2*DINNER) * DMODEL;       // 2M  (W_out)
    ushort_t* Wxb  = Wob  + (size_t)DMODEL * DINNER;           // 196608
    ushort_t* Wdtb = Wxb  + (size_t)XCOLS * DINNER;            // 131072
    ushort_t* xinb = Wdtb + (size_t)DINNER * DTRANK;           // 4M  (pre-conv x)
    ushort_t* gz   = xinb + (size_t)LSEQ * DINNER;             // 4M  (silu(z))
    ushort_t* xcb  = gz   + (size_t)LSEQ * DINNER;             // 4M  (x_conv)
    ushort_t* dtmb = xcb  + (size_t)LSEQ * DINNER;             // 4M  (dt)
    ushort_t* yb   = dtmb + (size_t)LSEQ * DINNER;             // 4M  (y)
    // out_proj SK4 fp32 partials: 4 x 8 MB over the post-phase3-dead
    // xinb+gz+xcb+dtmb region (32 MB contiguous). yb stays live.
    float* outp = (float*)xinb;

    // 0. fused casts to bf16 (x, W_in, W_out, W_x, W_dt) + zero xdbl
    {
        int c0 = LSEQ * DMODEL, c1 = 2 * DINNER * DMODEL, c2 = DMODEL * DINNER;
        int c3 = XCOLS * DINNER, c4 = DINNER * DTRANK;
        int cz = LSEQ * XCOLS;
        int total = c0 + c1 + c2 + c3 + c4 + cz;
        hipLaunchKernelGGL(cast6_kernel, dim3((total / 8 + 255) / 256), dim3(256), 0, stream,
                           x, xb, c0, W_in, Wib, c1, W_out, Wob, c2,
                           W_x, Wxb, c3, W_dt, Wdtb, c4, xdbl, cz);
    }

    // 1. in_proj (2048 x 4096), fused epilogue: x-half -> xinb, z-half -> gz
    hipLaunchKernelGGL((gemm_bf16<1,1>), dim3(LSEQ/128, (2*DINNER)/128), dim3(256), 0, stream,
                       xb, Wib, (float*)nullptr, xinb, gz, LSEQ, 2*DINNER, DMODEL, (size_t)0);

    // 2. depthwise conv + SiLU (bf16 in / bf16 out)
    hipLaunchKernelGGL(conv_silu_kernel, dim3((LSEQ*DINNER)/256), dim3(256), 0, stream,
                       xinb, conv_w, conv_b, xcb);

    // 3. x_dbl = xc @ W_x^T  (2048 x 96), direct-fragment MFMA, split-K=16
    hipLaunchKernelGGL(gemm_xdbl, dim3(LSEQ/128, 1, 16), dim3(256), 0, stream,
                       xcb, Wxb, xdbl);

    // 4. dt = softplus(x_dbl[:, :64] @ W_dt^T + b_dt) -> bf16
    hipLaunchKernelGGL(gemm_dt, dim3(LSEQ/128, DINNER/128), dim3(256), 0, stream,
                       xdbl, Wdtb, b_dt, dtmb);

    // 5. chunked parallel scan, CL=64; wave-parallel phase2 (Hillis-Steele)
    hipLaunchKernelGGL(scan_phase1, dim3(DINNER/256, NC), dim3(256), 0, stream,
                       dtmb, xdbl, xcb, A_log, state);
    hipLaunchKernelGGL(scan_phase2, dim3(SSTATE/8), dim3(256), 0, stream,
                       state);
    hipLaunchKernelGGL(scan_phase3, dim3(DINNER/256, NC), dim3(256), 0, stream,
                       dtmb, xdbl, xcb, A_log, D_par, gz, state, yb);

    // 6. out = y @ W_out^T  (2048 x 1024): SK4 (512 blocks = 2/CU, the
    //    measured 9 B/cy/CU regime), fp32 partials into dead region + add4.
    hipLaunchKernelGGL((gemm_bf16<0,4>), dim3(LSEQ/128, DMODEL/128, 4), dim3(256), 0, stream,
                       yb, Wob, outp, (ushort_t*)nullptr, (ushort_t*)nullptr,
                       LSEQ, DMODEL, DINNER, (size_t)(LSEQ*DMODEL));
    hipLaunchKernelGGL((addp_kernel<4>), dim3((LSEQ*DMODEL/4)/256), dim3(256), 0, stream,
                       outp, out, LSEQ*DMODEL);
}

// Round 16
// 203.298 us; speedup vs baseline: 1.0407x; 1.0407x over previous
//
#include <hip/hip_runtime.h>
#include <math.h>

#define LSEQ   2048
#define DMODEL 1024
#define DINNER 2048
#define DSTATE 16
#define DTRANK 64
#define XCOLS  96   // dt_rank + 2*d_state
#define CL     32   // scan chunk length
#define NC     (LSEQ/CL)          // 64 chunks
#define SSTATE (DINNER*DSTATE)    // 32768 scalar recurrences

typedef __attribute__((ext_vector_type(8))) short bf16x8;
typedef __attribute__((ext_vector_type(4))) float f32x4;
typedef unsigned short ushort_t;
typedef unsigned int uint_t;

__device__ __forceinline__ float siluf(float v) { return v / (1.f + __expf(-v)); }

// RNE float -> bf16 bits (finite inputs)
__device__ __forceinline__ ushort_t f2bf(float f) {
    uint_t u = __float_as_uint(f);
    u += 0x7FFFu + ((u >> 16) & 1u);
    return (ushort_t)(u >> 16);
}
__device__ __forceinline__ float bf2f(ushort_t u) {
    return __uint_as_float((uint_t)u << 16);
}

__device__ __forceinline__ bf16x8 cvt8(float4 lo, float4 hi) {
    bf16x8 r;
    r[0] = (short)f2bf(lo.x); r[1] = (short)f2bf(lo.y);
    r[2] = (short)f2bf(lo.z); r[3] = (short)f2bf(lo.w);
    r[4] = (short)f2bf(hi.x); r[5] = (short)f2bf(hi.y);
    r[6] = (short)f2bf(hi.z); r[7] = (short)f2bf(hi.w);
    return r;
}

// ---------------------------------------------------------------------------
// fused f32 -> bf16 cast for 5 tensors + zero-fill of xdbl.
// ---------------------------------------------------------------------------
__global__ __launch_bounds__(256)
void cast6_kernel(const float* __restrict__ s0, ushort_t* __restrict__ d0, int c0,
                  const float* __restrict__ s1, ushort_t* __restrict__ d1, int c1,
                  const float* __restrict__ s2, ushort_t* __restrict__ d2, int c2,
                  const float* __restrict__ s3, ushort_t* __restrict__ d3, int c3,
                  const float* __restrict__ s4, ushort_t* __restrict__ d4, int c4,
                  float* __restrict__ z0, int cz)
{
    int i = (blockIdx.x * 256 + threadIdx.x) * 8;
    int tot = c0 + c1 + c2 + c3 + c4;
    if (i < tot) {
        const float* s; ushort_t* d;
        if (i < c0)                { s = s0 + i;                  d = d0 + i; }
        else if (i < c0+c1)        { s = s1 + (i-c0);             d = d1 + (i-c0); }
        else if (i < c0+c1+c2)     { s = s2 + (i-c0-c1);          d = d2 + (i-c0-c1); }
        else if (i < c0+c1+c2+c3)  { s = s3 + (i-c0-c1-c2);       d = d3 + (i-c0-c1-c2); }
        else                       { s = s4 + (i-c0-c1-c2-c3);    d = d4 + (i-c0-c1-c2-c3); }
        *(bf16x8*)d = cvt8(*(const float4*)s, *(const float4*)(s + 4));
    } else if (i < tot + cz) {
        float* z = z0 + (i - tot);
        *(float4*)z       = make_float4(0.f, 0.f, 0.f, 0.f);
        *(float4*)(z + 4) = make_float4(0.f, 0.f, 0.f, 0.f);
    }
}

// ---------------------------------------------------------------------------
// bf16 MFMA GEMM — r5 measured-best loop (2-phase dbuf, BK=32, vmcnt(4),
// no swizzle, no split-K for EPI=1; SK via partStride for EPI=0).
// EPI=0: fp32 store (full 64B lines, no RMW).
// EPI=1: in_proj fused epilogue via LDS transpose -> FULL-LINE bf16 stores
//        (fixes r14/r15's +14.4 MB write-allocate RMW overfetch).
// LDS per buf: [4 kb][128 row][8 elem] -> SQ_LDS_BANK_CONFLICT == 0.
// ---------------------------------------------------------------------------
__device__ __forceinline__ void stage_tile(const ushort_t* __restrict__ A,
                                           const ushort_t* __restrict__ B,
                                           ushort_t* As, ushort_t* Bs,
                                           int m0, int n0, int K, int k0, int tid)
{
#pragma unroll
    for (int j = 0; j < 2; j++) {
        const int c   = j * 256 + tid;   // 16B chunk index 0..511
        const int row = c & 127;
        const int kbi = c >> 7;          // 0..3
        __builtin_amdgcn_global_load_lds(
            (const __attribute__((address_space(1))) uint_t*)(A + (size_t)(m0 + row) * K + k0 + kbi * 8),
            (__attribute__((address_space(3))) uint_t*)((char*)As + c * 16), 16, 0, 0);
        __builtin_amdgcn_global_load_lds(
            (const __attribute__((address_space(1))) uint_t*)(B + (size_t)(n0 + row) * K + k0 + kbi * 8),
            (__attribute__((address_space(3))) uint_t*)((char*)Bs + c * 16), 16, 0, 0);
    }
}

template<int EPI, int SPLITK>
__global__ __launch_bounds__(256)
void gemm_bf16(const ushort_t* __restrict__ A,
               const ushort_t* __restrict__ B,
               float* __restrict__ C,
               ushort_t* __restrict__ Xb,
               ushort_t* __restrict__ Gz,
               int M, int N, int K, size_t partStride)
{
    __shared__ ushort_t As[2][4096];
    __shared__ ushort_t Bs[2][4096];

    const int tid  = threadIdx.x;
    const int wid  = tid >> 6;
    const int lane = tid & 63;
    const int m0 = blockIdx.x * 128;
    const int n0 = blockIdx.y * 128;
    const int kcnt  = K / SPLITK;
    const int kbase = (SPLITK > 1) ? blockIdx.z * kcnt : 0;
    const int NT = kcnt / 32;
    float* Cp = (EPI == 0) ? C + (size_t)blockIdx.z * partStride : C;
    const int wr = (wid >> 1) * 64;
    const int wc = (wid & 1) * 64;
    const int lr = lane & 15;
    const int kbq = lane >> 4;

    f32x4 acc[4][4];
#pragma unroll
    for (int m = 0; m < 4; m++)
#pragma unroll
        for (int n = 0; n < 4; n++)
            acc[m][n] = (f32x4){0.f, 0.f, 0.f, 0.f};

    stage_tile(A, B, As[0], Bs[0], m0, n0, K, kbase, tid);

    for (int t = 0; t < NT; t++) {
        const int cur = t & 1;
        if (t + 1 < NT) {
            stage_tile(A, B, As[cur ^ 1], Bs[cur ^ 1], m0, n0, K, kbase + (t + 1) * 32, tid);
            asm volatile("s_waitcnt vmcnt(4)" ::: "memory");
        } else {
            asm volatile("s_waitcnt vmcnt(0)" ::: "memory");
        }
        __builtin_amdgcn_s_barrier();
        __builtin_amdgcn_sched_barrier(0);

        bf16x8 af[4], bfr[4];
#pragma unroll
        for (int m = 0; m < 4; m++)
            af[m] = *(const bf16x8*)&As[cur][(kbq * 128 + wr + m * 16 + lr) * 8];
#pragma unroll
        for (int n = 0; n < 4; n++)
            bfr[n] = *(const bf16x8*)&Bs[cur][(kbq * 128 + wc + n * 16 + lr) * 8];
#pragma unroll
        for (int m = 0; m < 4; m++)
#pragma unroll
            for (int n = 0; n < 4; n++)
                acc[m][n] = __builtin_amdgcn_mfma_f32_16x16x32_bf16(af[m], bfr[n], acc[m][n], 0, 0, 0);

        __builtin_amdgcn_sched_barrier(0);
        __builtin_amdgcn_s_barrier();
    }

    const int er = (lane >> 4) * 4;
    const int ec = lane & 15;
    if (EPI == 0) {
#pragma unroll
        for (int m = 0; m < 4; m++) {
            const int grow = m0 + wr + m * 16 + er;
#pragma unroll
            for (int n = 0; n < 4; n++) {
                const int gcol = n0 + wc + n * 16 + ec;
#pragma unroll
                for (int r = 0; r < 4; r++)
                    Cp[(size_t)(grow + r) * N + gcol] = acc[m][n][r];
            }
        }
    } else {
        // LDS-transpose epilogue: per-wave 64x64 bf16 tile, XOR-swizzled cols
        // (col' = col ^ ((row&7)*8)) to break the 128B-row-stride bank clash.
        const bool xside = (n0 < DINNER);   // uniform per block
        ushort_t* eps = (wid < 2) ? As[wid] : Bs[wid - 2];
#pragma unroll
        for (int m = 0; m < 4; m++)
#pragma unroll
            for (int n = 0; n < 4; n++)
#pragma unroll
                for (int r = 0; r < 4; r++) {
                    const int rl = m * 16 + er + r;
                    const int cl = n * 16 + ec;
                    float v = acc[m][n][r];
                    eps[rl * 64 + (cl ^ ((rl & 7) * 8))] =
                        xside ? f2bf(v) : f2bf(siluf(v));
                }
        __syncthreads();
        const int row8 = lane >> 3;
        const int c8   = (lane & 7) * 8;
#pragma unroll
        for (int p = 0; p < 8; p++) {
            const int rl = p * 8 + row8;
            bf16x8 v = *(const bf16x8*)&eps[rl * 64 + (c8 ^ ((rl & 7) * 8))];
            const int grow = m0 + wr + rl;
            const int gcol = n0 + wc + c8;
            if (xside)
                *(bf16x8*)(Xb + (size_t)grow * DINNER + gcol) = v;
            else
                *(bf16x8*)(Gz + (size_t)grow * DINNER + (gcol - DINNER)) = v;
        }
    }
}

// ---------------------------------------------------------------------------
// out = p0 + p1 (two fp32 partials), float4 per thread.
// ---------------------------------------------------------------------------
__global__ __launch_bounds__(256)
void add2_kernel(const float* __restrict__ p0, const float* __restrict__ p1,
                 float* __restrict__ out, int n)
{
    int i = (blockIdx.x * 256 + threadIdx.x) * 4;
    if (i >= n) return;
    float4 a = *(const float4*)(p0 + i);
    float4 b = *(const float4*)(p1 + i);
    *(float4*)(out + i) = make_float4(a.x + b.x, a.y + b.y, a.z + b.z, a.w + b.w);
}

// ---------------------------------------------------------------------------
// x_dbl GEMM: direct-fragment MFMA, split-K=16, fp32 atomics on 786 KB output.
// ---------------------------------------------------------------------------
__global__ __launch_bounds__(256)
void gemm_xdbl(const ushort_t* __restrict__ A,
               const ushort_t* __restrict__ B,
               float* __restrict__ Cout)
{
    const int tid = threadIdx.x, wid = tid >> 6, lane = tid & 63;
    const int m0 = blockIdx.x * 128;
    const int kbase = blockIdx.z * 128;
    const int wr = (wid >> 1) * 64;
    const int wc = (wid & 1) * 48;
    const int lr = lane & 15;
    const int kq = (lane >> 4) * 8;

    f32x4 acc[4][3];
#pragma unroll
    for (int m = 0; m < 4; m++)
#pragma unroll
        for (int n = 0; n < 3; n++)
            acc[m][n] = (f32x4){0.f, 0.f, 0.f, 0.f};

#pragma unroll
    for (int ks = 0; ks < 4; ks++) {
        const int k0 = kbase + ks * 32;
        bf16x8 af[4], bfr[3];
#pragma unroll
        for (int m = 0; m < 4; m++)
            af[m] = *(const bf16x8*)(A + (size_t)(m0 + wr + m * 16 + lr) * DINNER + k0 + kq);
#pragma unroll
        for (int n = 0; n < 3; n++)
            bfr[n] = *(const bf16x8*)(B + (size_t)(wc + n * 16 + lr) * DINNER + k0 + kq);
#pragma unroll
        for (int m = 0; m < 4; m++)
#pragma unroll
            for (int n = 0; n < 3; n++)
                acc[m][n] = __builtin_amdgcn_mfma_f32_16x16x32_bf16(af[m], bfr[n], acc[m][n], 0, 0, 0);
    }

    const int er = (lane >> 4) * 4;
    const int ec = lane & 15;
#pragma unroll
    for (int m = 0; m < 4; m++)
#pragma unroll
        for (int n = 0; n < 3; n++)
#pragma unroll
            for (int r = 0; r < 4; r++)
                atomicAdd(&Cout[(size_t)(m0 + wr + m * 16 + er + r) * XCOLS + wc + n * 16 + ec],
                          acc[m][n][r]);
}

// ---------------------------------------------------------------------------
// dt GEMM: dtmb = bf16(softplus(xdbl[:, :64] @ Wdtb^T + b_dt)).
// LDS-transpose epilogue -> full-line bf16 stores (same RMW fix as in_proj).
// ---------------------------------------------------------------------------
__global__ __launch_bounds__(256)
void gemm_dt(const float* __restrict__ Axd,
             const ushort_t* __restrict__ Bw,
             const float* __restrict__ bias,
             ushort_t* __restrict__ dtmb)
{
    __shared__ ushort_t eps4[4][4096];
    const int tid = threadIdx.x, wid = tid >> 6, lane = tid & 63;
    const int m0 = blockIdx.x * 128;
    const int n0 = blockIdx.y * 128;
    const int wr = (wid >> 1) * 64;
    const int wc = (wid & 1) * 64;
    const int lr = lane & 15;
    const int kq = (lane >> 4) * 8;

    f32x4 acc[4][4];
#pragma unroll
    for (int m = 0; m < 4; m++)
#pragma unroll
        for (int n = 0; n < 4; n++)
            acc[m][n] = (f32x4){0.f, 0.f, 0.f, 0.f};

#pragma unroll
    for (int kk = 0; kk < 2; kk++) {
        bf16x8 af[4], bfr[4];
#pragma unroll
        for (int m = 0; m < 4; m++) {
            const float* p = Axd + (size_t)(m0 + wr + m * 16 + lr) * XCOLS + kk * 32 + kq;
            af[m] = cvt8(*(const float4*)p, *(const float4*)(p + 4));
        }
#pragma unroll
        for (int n = 0; n < 4; n++)
            bfr[n] = *(const bf16x8*)(Bw + (size_t)(n0 + wc + n * 16 + lr) * DTRANK + kk * 32 + kq);
#pragma unroll
        for (int m = 0; m < 4; m++)
#pragma unroll
            for (int n = 0; n < 4; n++)
                acc[m][n] = __builtin_amdgcn_mfma_f32_16x16x32_bf16(af[m], bfr[n], acc[m][n], 0, 0, 0);
    }

    const int er = (lane >> 4) * 4;
    const int ec = lane & 15;
    ushort_t* eps = eps4[wid];
#pragma unroll
    for (int m = 0; m < 4; m++)
#pragma unroll
        for (int n = 0; n < 4; n++) {
            const int cl = n * 16 + ec;
            const float bv = bias[n0 + wc + cl];
#pragma unroll
            for (int r = 0; r < 4; r++) {
                const int rl = m * 16 + er + r;
                float c = acc[m][n][r] + bv;
                c = (c > 20.f) ? c : log1pf(__expf(c));
                eps[rl * 64 + (cl ^ ((rl & 7) * 8))] = f2bf(c);
            }
        }
    __syncthreads();
    const int row8 = lane >> 3;
    const int c8   = (lane & 7) * 8;
#pragma unroll
    for (int p = 0; p < 8; p++) {
        const int rl = p * 8 + row8;
        bf16x8 v = *(const bf16x8*)&eps[rl * 64 + (c8 ^ ((rl & 7) * 8))];
        dtmb[(size_t)(m0 + wr + rl) * DINNER + n0 + wc + c8] = 0; // placeholder overwritten below
        *(bf16x8*)(dtmb + (size_t)(m0 + wr + rl) * DINNER + n0 + wc + c8) = v;
    }
}

// ---------------------------------------------------------------------------
// Depthwise causal conv (width 4) + bias + SiLU, all-bf16 I/O.
// ---------------------------------------------------------------------------
__global__ __launch_bounds__(256)
void conv_silu_kernel(const ushort_t* __restrict__ xinb,
                      const float* __restrict__ conv_w,
                      const float* __restrict__ conv_b,
                      ushort_t* __restrict__ xcb)
{
    int idx = blockIdx.x * 256 + threadIdx.x;
    if (idx >= LSEQ * DINNER) return;
    int t = idx / DINNER;
    int d = idx - t * DINNER;
    float acc = conv_b[d];
#pragma unroll
    for (int j = 0; j < 4; j++) {
        int tt = t - 3 + j;
        if (tt >= 0)
            acc = fmaf(conv_w[d*4 + j], bf2f(xinb[(size_t)tt * DINNER + d]), acc);
    }
    xcb[idx] = f2bf(siluf(acc));
}

// ---------------------------------------------------------------------------
// Chunked parallel selective scan, CL=32, packed float2 state {Aprod, h}.
// ---------------------------------------------------------------------------
__global__ __launch_bounds__(256)
void scan_phase1(const ushort_t* __restrict__ dtmb,
                 const float* __restrict__ xdbl,
                 const ushort_t* __restrict__ xcb,
                 const float* __restrict__ A_log,
                 float2* __restrict__ state)
{
    __shared__ float Bs[CL][16];
    const int tid = threadIdx.x;
    const int d = blockIdx.x * 256 + tid;
    const int c = blockIdx.y;
    const int t0 = c * CL;

    {
        int t = tid >> 3, n = (tid * 2) & 15;
        float2 v = *(const float2*)&xdbl[(size_t)(t0 + t) * XCOLS + DTRANK + n];
        Bs[t][n] = v.x; Bs[t][n + 1] = v.y;
    }

    float a[16];
#pragma unroll
    for (int q = 0; q < 4; q++) {
        f32x4 v = *(const f32x4*)&A_log[(size_t)d * DSTATE + q * 4];
#pragma unroll
        for (int j = 0; j < 4; j++) a[q * 4 + j] = -__expf(v[j]);
    }
    float h[16];
#pragma unroll
    for (int n = 0; n < 16; n++) h[n] = 0.f;
    float sdt = 0.f;

    __syncthreads();

    float dtv = bf2f(dtmb[(size_t)t0 * DINNER + d]);
    float xv  = bf2f(xcb[(size_t)t0 * DINNER + d]);
    for (int tt = 0; tt < CL; tt++) {
        int tn_ = t0 + ((tt + 1 < CL) ? tt + 1 : tt);
        float dtv_n = bf2f(dtmb[(size_t)tn_ * DINNER + d]);
        float xv_n  = bf2f(xcb[(size_t)tn_ * DINNER + d]);

        f32x4 Bq[4];
#pragma unroll
        for (int q = 0; q < 4; q++) Bq[q] = *(const f32x4*)&Bs[tt][q * 4];
        float dtx = dtv * xv;
        sdt += dtv;
#pragma unroll
        for (int n = 0; n < 16; n++) {
            float e = __expf(dtv * a[n]);
            h[n] = fmaf(e, h[n], dtx * Bq[n >> 2][n & 3]);
        }
        dtv = dtv_n; xv = xv_n;
    }

#pragma unroll
    for (int n = 0; n < 16; n++)
        state[(size_t)c * SSTATE + (size_t)n * DINNER + d] =
            make_float2(__expf(a[n] * sdt), h[n]);
}

__global__ __launch_bounds__(256)
void scan_phase2(float2* __restrict__ state)
{
    const int idx = blockIdx.x * 256 + threadIdx.x;   // chain id
    float carry = 0.f;
#pragma unroll
    for (int c = 0; c < NC; c++) {
        float2 s = state[(size_t)c * SSTATE + idx];
        ((float*)&state[(size_t)c * SSTATE + idx])[1] = carry;
        carry = fmaf(s.x, carry, s.y);
    }
}

__global__ __launch_bounds__(256)
void scan_phase3(const ushort_t* __restrict__ dtmb,
                 const float* __restrict__ xdbl,
                 const ushort_t* __restrict__ xcb,
                 const float* __restrict__ A_log,
                 const float* __restrict__ Dp,
                 const ushort_t* __restrict__ gz,
                 const float2* __restrict__ state,
                 ushort_t* __restrict__ yb)
{
    __shared__ float Bs[CL][16];
    __shared__ float Cs[CL][16];
    const int tid = threadIdx.x;
    const int d = blockIdx.x * 256 + tid;
    const int c = blockIdx.y;
    const int t0 = c * CL;

    {
        int r = tid & 127;
        int t = r >> 2, n = (r * 4) & 15;
        const float* src = &xdbl[(size_t)(t0 + t) * XCOLS + DTRANK + ((tid < 128) ? 0 : DSTATE) + n];
        float4 v = *(const float4*)src;
        float* dst = (tid < 128) ? &Bs[t][n] : &Cs[t][n];
        dst[0] = v.x; dst[1] = v.y; dst[2] = v.z; dst[3] = v.w;
    }

    float a[16];
#pragma unroll
    for (int q = 0; q < 4; q++) {
        f32x4 v = *(const f32x4*)&A_log[(size_t)d * DSTATE + q * 4];
#pragma unroll
        for (int j = 0; j < 4; j++) a[q * 4 + j] = -__expf(v[j]);
    }
    const float Dv = Dp[d];
    float h[16];
#pragma unroll
    for (int n = 0; n < 16; n++)
        h[n] = state[(size_t)c * SSTATE + (size_t)n * DINNER + d].y;

    __syncthreads();

    float dtv = bf2f(dtmb[(size_t)t0 * DINNER + d]);
    float xv  = bf2f(xcb[(size_t)t0 * DINNER + d]);
    for (int tt = 0; tt < CL; tt++) {
        const int t = t0 + tt;
        int tn_ = t0 + ((tt + 1 < CL) ? tt + 1 : tt);
        float dtv_n = bf2f(dtmb[(size_t)tn_ * DINNER + d]);
        float xv_n  = bf2f(xcb[(size_t)tn_ * DINNER + d]);
        float gzv   = bf2f(gz[(size_t)t * DINNER + d]);

        f32x4 Bq[4], Cq[4];
#pragma unroll
        for (int q = 0; q < 4; q++) {
            Bq[q] = *(const f32x4*)&Bs[tt][q * 4];
            Cq[q] = *(const f32x4*)&Cs[tt][q * 4];
        }
        float dtx = dtv * xv;
        float y = 0.f;
#pragma unroll
        for (int n = 0; n < 16; n++) {
            float e = __expf(dtv * a[n]);
            h[n] = fmaf(e, h[n], dtx * Bq[n >> 2][n & 3]);
            y = fmaf(h[n], Cq[n >> 2][n & 3], y);
        }
        yb[(size_t)t * DINNER + d] = f2bf((y + Dv * xv) * gzv);
        dtv = dtv_n; xv = xv_n;
    }
}

// ---------------------------------------------------------------------------
extern "C" void kernel_launch(void* const* d_in, const int* in_sizes, int n_in,
                              void* d_out, int out_size, void* d_ws, size_t ws_size,
                              hipStream_t stream)
{
    const float* x      = (const float*)d_in[0];
    const float* W_in   = (const float*)d_in[1];
    const float* conv_w = (const float*)d_in[2];
    const float* conv_b = (const float*)d_in[3];
    const float* W_x    = (const float*)d_in[4];
    const float* W_dt   = (const float*)d_in[5];
    const float* b_dt   = (const float*)d_in[6];
    const float* A_log  = (const float*)d_in[7];
    const float* D_par  = (const float*)d_in[8];
    const float* W_out  = (const float*)d_in[9];
    float* out = (float*)d_out;
    float* ws  = (float*)d_ws;

    // fp32 region
    float*  xdbl  = ws;                                        // 196608 f32
    float2* state = (float2*)(xdbl + (size_t)LSEQ * XCOLS);    // NC*SSTATE f2 = 16 MB
    // bf16 region
    ushort_t* xb   = (ushort_t*)(state + (size_t)NC * SSTATE); // 2M  (x cast)
    ushort_t* Wib  = xb   + (size_t)LSEQ * DMODEL;             // 4M  (W_in)
    ushort_t* Wob  = Wib  + (size_t)(2*DINNER) * DMODEL;       // 2M  (W_out)
    ushort_t* Wxb  = Wob  + (size_t)DMODEL * DINNER;           // 196608
    ushort_t* Wdtb = Wxb  + (size_t)XCOLS * DINNER;            // 131072
    ushort_t* xinb = Wdtb + (size_t)DINNER * DTRANK;           // 4M  (pre-conv x)
    ushort_t* gz   = xinb + (size_t)LSEQ * DINNER;             // 4M  (silu(z))
    ushort_t* xcb  = gz   + (size_t)LSEQ * DINNER;             // 4M  (x_conv)
    ushort_t* dtmb = xcb  + (size_t)LSEQ * DINNER;             // 4M  (dt)
    ushort_t* yb   = dtmb + (size_t)LSEQ * DINNER;             // 4M  (y)
    // out_proj SK2 fp32 partials: 2 x 8 MB over xinb+gz (dead after phase3).
    float* outp = (float*)xinb;

    // 0. fused casts to bf16 (x, W_in, W_out, W_x, W_dt) + zero xdbl
    {
        int c0 = LSEQ * DMODEL, c1 = 2 * DINNER * DMODEL, c2 = DMODEL * DINNER;
        int c3 = XCOLS * DINNER, c4 = DINNER * DTRANK;
        int cz = LSEQ * XCOLS;
        int total = c0 + c1 + c2 + c3 + c4 + cz;
        hipLaunchKernelGGL(cast6_kernel, dim3((total / 8 + 255) / 256), dim3(256), 0, stream,
                           x, xb, c0, W_in, Wib, c1, W_out, Wob, c2,
                           W_x, Wxb, c3, W_dt, Wdtb, c4, xdbl, cz);
    }

    // 1. in_proj (2048 x 4096), fused epilogue (full-line bf16 stores):
    //    x-half -> xinb, z-half -> silu -> gz.
    hipLaunchKernelGGL((gemm_bf16<1,1>), dim3(LSEQ/128, (2*DINNER)/128), dim3(256), 0, stream,
                       xb, Wib, (float*)nullptr, xinb, gz, LSEQ, 2*DINNER, DMODEL, (size_t)0);

    // 2. depthwise conv + SiLU (bf16 in / bf16 out)
    hipLaunchKernelGGL(conv_silu_kernel, dim3((LSEQ*DINNER)/256), dim3(256), 0, stream,
                       xinb, conv_w, conv_b, xcb);

    // 3. x_dbl = xc @ W_x^T  (2048 x 96), direct-fragment MFMA, split-K=16
    hipLaunchKernelGGL(gemm_xdbl, dim3(LSEQ/128, 1, 16), dim3(256), 0, stream,
                       xcb, Wxb, xdbl);

    // 4. dt = softplus(x_dbl[:, :64] @ W_dt^T + b_dt) -> bf16 (full-line stores)
    hipLaunchKernelGGL(gemm_dt, dim3(LSEQ/128, DINNER/128), dim3(256), 0, stream,
                       xdbl, Wdtb, b_dt, dtmb);

    // 5. chunked parallel scan, CL=32 (512-block phases, 2 blocks/CU)
    hipLaunchKernelGGL(scan_phase1, dim3(DINNER/256, NC), dim3(256), 0, stream,
                       dtmb, xdbl, xcb, A_log, state);
    hipLaunchKernelGGL(scan_phase2, dim3(SSTATE/256), dim3(256), 0, stream,
                       state);
    hipLaunchKernelGGL(scan_phase3, dim3(DINNER/256, NC), dim3(256), 0, stream,
                       dtmb, xdbl, xcb, A_log, D_par, gz, state, yb);

    // 6. out = y @ W_out^T  (2048 x 1024): SK2 (r14-best), partials + add2
    hipLaunchKernelGGL((gemm_bf16<0,2>), dim3(LSEQ/128, DMODEL/128, 2), dim3(256), 0, stream,
                       yb, Wob, outp, (ushort_t*)nullptr, (ushort_t*)nullptr,
                       LSEQ, DMODEL, DINNER, (size_t)(LSEQ*DMODEL));
    hipLaunchKernelGGL(add2_kernel, dim3((LSEQ*DMODEL/4)/256), dim3(256), 0, stream,
                       outp, outp + (size_t)LSEQ*DMODEL, out, LSEQ*DMODEL);
}